// Round 4
// baseline (87.473 us; speedup 1.0000x reference)
//
#include <hip/hip_runtime.h>

// ViT block with "quantum" VQC layers on MI355X — float32 I/O.
//
// VQC closed form: the 8-qubit circuit (RX data layer + RX weight layer +
// CNOT ring) reduces exactly to prefix products of cos(x_i + W_i):
//   z_0 = prod_{i=1..7} cos(th_i),  z_k = prod_{i=0..k} cos(th_i)  (k>=1)
// (product state -> CNOT ring is a basis permutation -> bit k becomes parity
// of bits 0..k; expectations of parities of independent bits factorize).
//
// R4 structure: grid = B*4 = 256 blocks (1/CU). Block owns 64 query tokens.
// 512 threads = 16 query-quads x 2 heads x 16 key-splits of 16 keys.
// 4-query register blocking: one K/V read (2 x ds_read_b128) feeds 4
// score-exp-acc chains -> 4x fewer LDS reads than R3 (the R3 bottleneck).
// K/V stored head-interleaved K2[256][2][4] so the wave's 4 address groups
// hit disjoint bank quads (2-way aliasing only = free per m136).
// Scores bounded (|q.k|*0.5 <= 2) -> plain exp-sum, split partials add.

#define SEQ 256
#define EMB 8
#define QG  64     // query tokens per block
#define NSPLIT 16  // key splits
#define KS  16     // keys per split

static __device__ __forceinline__ void load8f(const float* __restrict__ p, float v[8]) {
    float4 a = *reinterpret_cast<const float4*>(p);
    float4 b = *reinterpret_cast<const float4*>(p + 4);
    v[0] = a.x; v[1] = a.y; v[2] = a.z; v[3] = a.w;
    v[4] = b.x; v[5] = b.y; v[6] = b.z; v[7] = b.w;
}

static __device__ __forceinline__ void store8f(float* __restrict__ p, const float v[8]) {
    *reinterpret_cast<float4*>(p)     = make_float4(v[0], v[1], v[2], v[3]);
    *reinterpret_cast<float4*>(p + 4) = make_float4(v[4], v[5], v[6], v[7]);
}

// Closed-form 8-qubit VQC (see header comment).
static __device__ __forceinline__ void vqc8(const float in[8], const float W[8], float z[8]) {
    float c[8];
#pragma unroll
    for (int i = 0; i < 8; ++i) c[i] = __cosf(in[i] + W[i]);
    float t = c[1];
#pragma unroll
    for (int i = 2; i < 8; ++i) t *= c[i];
    z[0] = t;
    float acc = c[0];
#pragma unroll
    for (int i = 1; i < 8; ++i) { acc *= c[i]; z[i] = acc; }
}

static __device__ __forceinline__ void ln8(const float r[8], const float g[8], const float be[8], float o[8]) {
    float m = 0.f;
#pragma unroll
    for (int i = 0; i < 8; ++i) m += r[i];
    m *= 0.125f;
    float var = 0.f;
#pragma unroll
    for (int i = 0; i < 8; ++i) { float d = r[i] - m; var += d * d; }
    var *= 0.125f;
    float inv = rsqrtf(var + 1e-5f);
#pragma unroll
    for (int i = 0; i < 8; ++i) o[i] = (r[i] - m) * inv * g[i] + be[i];
}

__global__ __launch_bounds__(512) void vitq_kernel(
    const float* __restrict__ x,
    const float* __restrict__ Wq, const float* __restrict__ Wk,
    const float* __restrict__ Wv, const float* __restrict__ Wc,
    const float* __restrict__ Wf,
    const float* __restrict__ w1, const float* __restrict__ b1,
    const float* __restrict__ w2, const float* __restrict__ b2,
    const float* __restrict__ g1, const float* __restrict__ be1,
    const float* __restrict__ g2, const float* __restrict__ be2,
    float* __restrict__ out)
{
    __shared__ float K2[SEQ][2][4];                 // 8 KB, head-interleaved
    __shared__ float V2[SEQ][2][4];                 // 8 KB
    __shared__ float P[NSPLIT][2][QG][5];           // 40 KB partials

    const int bi  = blockIdx.x;
    const int b   = bi >> 2;          // batch
    const int g   = bi & 3;           // query group (64 tokens)
    const int tid = threadIdx.x;
    const int qq  = tid & 15;         // query quad -> queries 4qq..4qq+3
    const int h   = (tid >> 4) & 1;   // head
    const int j   = tid >> 5;         // key split 0..15

    const float* xb = x + ((size_t)b * SEQ) * EMB;
    float wrow[8];

    // ---- stage K/V (head-interleaved) for all 256 tokens of batch b ----
    {
        const int t = tid & 255;
        float xs[8], kv[8];
        load8f(xb + (size_t)t * EMB, xs);
        if (tid < 256) {
            load8f(Wk, wrow);
            vqc8(xs, wrow, kv);
            store8f(&K2[t][0][0], kv);
        } else {
            load8f(Wv, wrow);
            vqc8(xs, wrow, kv);
            store8f(&V2[t][0][0], kv);
        }
    }

    // ---- Q for my 4 queries (head slice, 1/sqrt(dk) folded) ----
    float qh[4][4];
    load8f(Wq, wrow);
#pragma unroll
    for (int m = 0; m < 4; ++m) {
        const int s = g * QG + 4 * qq + m;
        float xq[8], q[8];
        load8f(xb + (size_t)s * EMB, xq);
        vqc8(xq, wrow, q);
#pragma unroll
        for (int d = 0; d < 4; ++d) qh[m][d] = q[4 * h + d] * 0.5f;
    }
    __syncthreads();

    // ---- attention partials: 4 queries x 16-key slice ----
    float l[4] = {0.f, 0.f, 0.f, 0.f};
    float a0[4] = {0.f, 0.f, 0.f, 0.f};
    float a1[4] = {0.f, 0.f, 0.f, 0.f};
    float a2[4] = {0.f, 0.f, 0.f, 0.f};
    float a3[4] = {0.f, 0.f, 0.f, 0.f};
#pragma unroll 4
    for (int i = 0; i < KS; ++i) {
        const int kk = j * KS + i;
        float4 kr = *reinterpret_cast<const float4*>(&K2[kk][h][0]);
        float4 vr = *reinterpret_cast<const float4*>(&V2[kk][h][0]);
#pragma unroll
        for (int m = 0; m < 4; ++m) {
            float sc = qh[m][0] * kr.x + qh[m][1] * kr.y + qh[m][2] * kr.z + qh[m][3] * kr.w;
            float e  = __expf(sc);
            l[m]  += e;
            a0[m] += e * vr.x;
            a1[m] += e * vr.y;
            a2[m] += e * vr.z;
            a3[m] += e * vr.w;
        }
    }
#pragma unroll
    for (int m = 0; m < 4; ++m) {
        float* pp = &P[j][h][4 * qq + m][0];
        pp[0] = l[m]; pp[1] = a0[m]; pp[2] = a1[m]; pp[3] = a2[m]; pp[4] = a3[m];
    }
    __syncthreads();

    // ---- reduce splits + tail, one thread per owned token ----
    if (tid < QG) {
        const int s = g * QG + tid;   // global token in batch
        float ctx[8];
#pragma unroll
        for (int hh = 0; hh < 2; ++hh) {
            float ll = 0.f, c0 = 0.f, c1 = 0.f, c2 = 0.f, c3 = 0.f;
#pragma unroll
            for (int jj = 0; jj < NSPLIT; ++jj) {
                const float* pp = &P[jj][hh][tid][0];
                ll += pp[0]; c0 += pp[1]; c1 += pp[2]; c2 += pp[3]; c3 += pp[4];
            }
            float inv = 1.f / ll;
            ctx[4 * hh + 0] = c0 * inv;
            ctx[4 * hh + 1] = c1 * inv;
            ctx[4 * hh + 2] = c2 * inv;
            ctx[4 * hh + 3] = c3 * inv;
        }

        float xq[8];
        load8f(xb + (size_t)s * EMB, xq);   // L2-hot reload for residual

        float ao[8];
        load8f(Wc, wrow);
        vqc8(ctx, wrow, ao);

        float r[8];
#pragma unroll
        for (int i = 0; i < 8; ++i) r[i] = xq[i] + ao[i];

        float gg[8], be[8], x1[8];
        load8f(g1, gg); load8f(be1, be);
        ln8(r, gg, be, x1);

        // hv = x1 @ w1.T + b1
        float wf[64], bias[8];
#pragma unroll
        for (int i = 0; i < 64; ++i) wf[i] = w1[i];
        load8f(b1, bias);
        float hv[8];
#pragma unroll
        for (int jj = 0; jj < 8; ++jj) {
            float a = bias[jj];
#pragma unroll
            for (int i = 0; i < 8; ++i) a += x1[i] * wf[jj * 8 + i];
            hv[jj] = a;
        }

        float hq[8];
        load8f(Wf, wrow);
        vqc8(hv, wrow, hq);

        // ff = hq @ w2.T + b2 ; residual ; LN2
#pragma unroll
        for (int i = 0; i < 64; ++i) wf[i] = w2[i];
        load8f(b2, bias);
        float r2[8];
#pragma unroll
        for (int jj = 0; jj < 8; ++jj) {
            float a = bias[jj];
#pragma unroll
            for (int i = 0; i < 8; ++i) a += hq[i] * wf[jj * 8 + i];
            r2[jj] = x1[jj] + a;
        }

        float o[8];
        load8f(g2, gg); load8f(be2, be);
        ln8(r2, gg, be, o);

        store8f(out + ((size_t)(b * SEQ + s)) * EMB, o);
    }
}

extern "C" void kernel_launch(void* const* d_in, const int* in_sizes, int n_in,
                              void* d_out, int out_size, void* d_ws, size_t ws_size,
                              hipStream_t stream) {
    const float* x   = (const float*)d_in[0];
    const float* Wq  = (const float*)d_in[1];
    const float* Wk  = (const float*)d_in[2];
    const float* Wv  = (const float*)d_in[3];
    const float* Wc  = (const float*)d_in[4];
    const float* Wf  = (const float*)d_in[5];
    const float* w1  = (const float*)d_in[6];
    const float* b1  = (const float*)d_in[7];
    const float* w2  = (const float*)d_in[8];
    const float* b2  = (const float*)d_in[9];
    const float* g1  = (const float*)d_in[10];
    const float* be1 = (const float*)d_in[11];
    const float* g2  = (const float*)d_in[12];
    const float* be2 = (const float*)d_in[13];
    float* out = (float*)d_out;

    const int B = in_sizes[0] / (SEQ * EMB);   // 64
    vitq_kernel<<<B * 4, 512, 0, stream>>>(x, Wq, Wk, Wv, Wc, Wf, w1, b1, w2, b2,
                                           g1, be1, g2, be2, out);
}